// Round 13
// baseline (667.797 us; speedup 1.0000x reference)
//
#include <hip/hip_runtime.h>

#define TPB 256
#define BK_SHIFT 7
#define BK_SIZE 128
#define NBK_MAX 800     // >= ceil(100000/128)=782
#define EPT 32          // edges per thread in bin_scatter chunks

typedef __attribute__((ext_vector_type(8))) short bf16x8;
typedef __attribute__((ext_vector_type(4))) float f32x4;

__device__ __forceinline__ unsigned short f2bf(float f) {
    unsigned u = __float_as_uint(f);
    unsigned r = (u + 0x7FFFu + ((u >> 16) & 1u)) >> 16;   // RNE
    return (unsigned short)r;
}
__device__ __forceinline__ float bf2f(unsigned short b) {
    return __uint_as_float((unsigned)b << 16);
}

// ---------------- bucket histogram (LDS-privatized, int4 loads) -----------
__global__ __launch_bounds__(256) void hist_buckets(
    const int* __restrict__ dst, int* __restrict__ bcnt, int E, int NBK)
{
    __shared__ int h[NBK_MAX];
    const int t = threadIdx.x;
    for (int i = t; i < NBK; i += 256) h[i] = 0;
    __syncthreads();
    const int E4 = E >> 2;
    for (int e4 = blockIdx.x * blockDim.x + t; e4 < E4; e4 += gridDim.x * blockDim.x) {
        int4 d = ((const int4*)dst)[e4];
        atomicAdd(&h[d.x >> BK_SHIFT], 1);
        atomicAdd(&h[d.y >> BK_SHIFT], 1);
        atomicAdd(&h[d.z >> BK_SHIFT], 1);
        atomicAdd(&h[d.w >> BK_SHIFT], 1);
    }
    if (blockIdx.x == 0) {
        for (int e = E4 * 4 + t; e < E; e += 256)
            atomicAdd(&h[dst[e] >> BK_SHIFT], 1);
    }
    __syncthreads();
    for (int i = t; i < NBK; i += 256)
        if (h[i]) atomicAdd(&bcnt[i], h[i]);
}

// ---------------- scan of bucket counts (one block, NBK<=1024) ------------
__global__ __launch_bounds__(1024) void scan_buckets(
    const int* __restrict__ bcnt, int* __restrict__ bbase,
    int* __restrict__ gcursor, int NBK)
{
    __shared__ int s[1024];
    const int t = threadIdx.x;
    int v = (t < NBK) ? bcnt[t] : 0;
    s[t] = v;
    __syncthreads();
    for (int off = 1; off < 1024; off <<= 1) {
        int u = (t >= off) ? s[t - off] : 0;
        __syncthreads();
        s[t] += u;
        __syncthreads();
    }
    if (t < NBK) {
        int excl = s[t] - v;
        bbase[t]   = excl;
        gcursor[t] = excl;
    }
}

// ---------------- bin scatter: pack edges into bucket-ordered pk[] --------
__global__ __launch_bounds__(256) void bin_scatter(
    const int* __restrict__ src, const int* __restrict__ dst,
    int* __restrict__ gcursor, int* __restrict__ pk, int E, int NBK)
{
    __shared__ int lcnt[NBK_MAX];
    __shared__ int lbase[NBK_MAX];
    __shared__ int lrank[NBK_MAX];
    const int t = threadIdx.x;
    const int e0 = blockIdx.x * (256 * EPT);

    for (int i = t; i < NBK; i += 256) { lcnt[i] = 0; lrank[i] = 0; }
    __syncthreads();

    #pragma unroll 4
    for (int k = 0; k < EPT; ++k) {
        int e = e0 + k * 256 + t;
        if (e < E) atomicAdd(&lcnt[dst[e] >> BK_SHIFT], 1);
    }
    __syncthreads();

    for (int i = t; i < NBK; i += 256) {
        int c = lcnt[i];
        if (c) lbase[i] = atomicAdd(&gcursor[i], c);
    }
    __syncthreads();

    #pragma unroll 4
    for (int k = 0; k < EPT; ++k) {
        int e = e0 + k * 256 + t;
        if (e < E) {
            int d = dst[e], s = src[e];
            int b = d >> BK_SHIFT;
            int r = atomicAdd(&lrank[b], 1);
            pk[lbase[b] + r] = (s << BK_SHIFT) | (d & (BK_SIZE - 1));
        }
    }
}

// ---------------- gemm1 via MFMA:  y1(bf16)=x@W1l,  c1=x@W1r+b1 -----------
__global__ __launch_bounds__(256) void gemm1_mfma(
    const float* __restrict__ A,      // x [N][128]
    const float* __restrict__ Wl,     // [128][32]
    const float* __restrict__ Wr,     // [128][32]
    const float* __restrict__ b,      // [32]
    unsigned short* __restrict__ Yb,  // y1 bf16 [N][32]
    float* __restrict__ C,            // c1 [N][32]
    int N)
{
    const int lane = threadIdx.x & 63;
    const int m    = lane & 15;
    const int quad = lane >> 4;
    const int wave   = blockIdx.x * (blockDim.x >> 6) + (threadIdx.x >> 6);
    const int nwaves = gridDim.x * (blockDim.x >> 6);
    const int ntiles = (N + 15) >> 4;

    bf16x8 Bf[4][4];   // [kc][jt]; jt 0,1 -> Wl; jt 2,3 -> Wr
    #pragma unroll
    for (int kc = 0; kc < 4; ++kc) {
        #pragma unroll
        for (int jt = 0; jt < 4; ++jt) {
            const float* W = (jt < 2) ? Wl : Wr;
            const int col = (jt & 1) * 16 + m;
            #pragma unroll
            for (int j = 0; j < 8; ++j) {
                int k = kc * 32 + quad * 8 + j;
                Bf[kc][jt][j] = (short)f2bf(W[k * 32 + col]);
            }
        }
    }

    const float bias0 = b[m];
    const float bias1 = b[16 + m];

    for (int tile = wave; tile < ntiles; tile += nwaves) {
        const int node0 = tile * 16;
        const int gn = node0 + m;
        const bool okA = gn < N;
        const float* rowp = A + (size_t)gn * 128;

        bf16x8 Af[4];
        #pragma unroll
        for (int kc = 0; kc < 4; ++kc) {
            float4 v0 = make_float4(0.f, 0.f, 0.f, 0.f);
            float4 v1 = make_float4(0.f, 0.f, 0.f, 0.f);
            if (okA) {
                v0 = *(const float4*)&rowp[kc * 32 + quad * 8];
                v1 = *(const float4*)&rowp[kc * 32 + quad * 8 + 4];
            }
            Af[kc][0] = (short)f2bf(v0.x); Af[kc][1] = (short)f2bf(v0.y);
            Af[kc][2] = (short)f2bf(v0.z); Af[kc][3] = (short)f2bf(v0.w);
            Af[kc][4] = (short)f2bf(v1.x); Af[kc][5] = (short)f2bf(v1.y);
            Af[kc][6] = (short)f2bf(v1.z); Af[kc][7] = (short)f2bf(v1.w);
        }

        f32x4 acc[4] = {{0.f,0.f,0.f,0.f},{0.f,0.f,0.f,0.f},
                        {0.f,0.f,0.f,0.f},{0.f,0.f,0.f,0.f}};
        #pragma unroll
        for (int kc = 0; kc < 4; ++kc) {
            #pragma unroll
            for (int jt = 0; jt < 4; ++jt)
                acc[jt] = __builtin_amdgcn_mfma_f32_16x16x32_bf16(
                    Af[kc], Bf[kc][jt], acc[jt], 0, 0, 0);
        }

        const int nodeBase = node0 + quad * 4;
        #pragma unroll
        for (int reg = 0; reg < 4; ++reg) {
            const int node = nodeBase + reg;
            if (node < N) {
                Yb[(size_t)node * 32 + m]      = f2bf(acc[0][reg]);
                Yb[(size_t)node * 32 + 16 + m] = f2bf(acc[1][reg]);
                C [(size_t)node * 32 + m]      = acc[2][reg] + bias0;
                C [(size_t)node * 32 + 16 + m] = acc[3][reg] + bias1;
            }
        }
    }
}

// ------- gather1+relu+gemm2, edge-parallel LDS accumulation ---------------
// Block b = bucket b (128 nodes). 8 lanes per edge; LDS acc[128][33].
// NATIVE ds_add_f32 via unsafeAtomicAdd (R12's CAS-loop was the 8x killer).
__global__ __launch_bounds__(256) void gather_gemm2(
    const int* __restrict__ bbase, const int* __restrict__ bcnt,
    const int* __restrict__ pk,
    const unsigned short* __restrict__ Yb,  // y1 bf16 [N][32]
    const float* __restrict__ c1,           // [N][32]
    const float* __restrict__ W2l, const float* __restrict__ W2r,
    const float* __restrict__ b2,
    float* __restrict__ invdeg,             // [N] out
    unsigned short* __restrict__ y2b, float* __restrict__ c2, int N)
{
    __shared__ float acc[BK_SIZE * 33];
    __shared__ int   ldeg[BK_SIZE];

    const int t = threadIdx.x;
    const int b = blockIdx.x;
    const int base = bbase[b];
    const int cnt  = bcnt[b];
    const int node0 = b * BK_SIZE;

    for (int i = t; i < BK_SIZE * 33; i += 256) acc[i] = 0.f;
    if (t < BK_SIZE) ldeg[t] = 0;
    __syncthreads();

    const int sg = t >> 3;        // 32 edge-slots
    const int q  = t & 7;

    for (int e = sg; e < cnt; e += 32) {
        int pkv = pk[base + e];
        int s   = pkv >> BK_SHIFT;
        int dl  = pkv & (BK_SIZE - 1);
        ushort4 v = *(const ushort4*)&Yb[(size_t)s * 32 + q * 4];
        float* ap = &acc[dl * 33 + q * 4];
        unsafeAtomicAdd(ap + 0, bf2f(v.x));
        unsafeAtomicAdd(ap + 1, bf2f(v.y));
        unsafeAtomicAdd(ap + 2, bf2f(v.z));
        unsafeAtomicAdd(ap + 3, bf2f(v.w));
        if (q == 0) atomicAdd(&ldeg[dl], 1);
    }
    __syncthreads();

    // h = relu(c1 + acc*w), stored back into acc; write invdeg
    if (t < BK_SIZE) {
        int node = node0 + t;
        if (node < N) {
            float w = 1.0f / fmaxf((float)ldeg[t], 1.0f);
            invdeg[node] = w;
            const float* crow = &c1[(size_t)node * 32];
            #pragma unroll
            for (int k = 0; k < 32; ++k)
                acc[t * 33 + k] = fmaxf(crow[k] + acc[t * 33 + k] * w, 0.f);
        }
    }
    __syncthreads();

    // matvec: part 0 -> y2b = h@W2l (bf16); part 1 -> c2 = h@W2r + b2
    {
        const int node = t & (BK_SIZE - 1);
        const int part = t >> 7;
        const int gn = node0 + node;
        if (gn < N) {
            const float* W = part ? W2r : W2l;
            f32x4 o0 = {0,0,0,0}, o1 = {0,0,0,0}, o2 = {0,0,0,0}, o3 = {0,0,0,0};
            #pragma unroll
            for (int k = 0; k < 32; ++k) {
                float hk = acc[node * 33 + k];
                float4 w0 = *(const float4*)&W[k * 16 + 0];
                float4 w1 = *(const float4*)&W[k * 16 + 4];
                float4 w2 = *(const float4*)&W[k * 16 + 8];
                float4 w3 = *(const float4*)&W[k * 16 + 12];
                o0[0] += hk * w0.x; o0[1] += hk * w0.y; o0[2] += hk * w0.z; o0[3] += hk * w0.w;
                o1[0] += hk * w1.x; o1[1] += hk * w1.y; o1[2] += hk * w1.z; o1[3] += hk * w1.w;
                o2[0] += hk * w2.x; o2[1] += hk * w2.y; o2[2] += hk * w2.z; o2[3] += hk * w2.w;
                o3[0] += hk * w3.x; o3[1] += hk * w3.y; o3[2] += hk * w3.z; o3[3] += hk * w3.w;
            }
            if (part == 0) {
                ushort4 r0, r1, r2, r3;
                r0.x = f2bf(o0[0]); r0.y = f2bf(o0[1]); r0.z = f2bf(o0[2]); r0.w = f2bf(o0[3]);
                r1.x = f2bf(o1[0]); r1.y = f2bf(o1[1]); r1.z = f2bf(o1[2]); r1.w = f2bf(o1[3]);
                r2.x = f2bf(o2[0]); r2.y = f2bf(o2[1]); r2.z = f2bf(o2[2]); r2.w = f2bf(o2[3]);
                r3.x = f2bf(o3[0]); r3.y = f2bf(o3[1]); r3.z = f2bf(o3[2]); r3.w = f2bf(o3[3]);
                ushort4* yp = (ushort4*)&y2b[(size_t)gn * 16];
                yp[0] = r0; yp[1] = r1; yp[2] = r2; yp[3] = r3;
            } else {
                float4* cp = (float4*)&c2[(size_t)gn * 16];
                float4 bb0 = *(const float4*)&b2[0];
                float4 bb1 = *(const float4*)&b2[4];
                float4 bb2 = *(const float4*)&b2[8];
                float4 bb3 = *(const float4*)&b2[12];
                cp[0] = make_float4(o0[0]+bb0.x, o0[1]+bb0.y, o0[2]+bb0.z, o0[3]+bb0.w);
                cp[1] = make_float4(o1[0]+bb1.x, o1[1]+bb1.y, o1[2]+bb1.z, o1[3]+bb1.w);
                cp[2] = make_float4(o2[0]+bb2.x, o2[1]+bb2.y, o2[2]+bb2.z, o2[3]+bb2.w);
                cp[3] = make_float4(o3[0]+bb3.x, o3[1]+bb3.y, o3[2]+bb3.z, o3[3]+bb3.w);
            }
        }
    }
}

// ------- gather2+final, edge-parallel LDS accumulation --------------------
// Block b = bucket b. 4 lanes per edge; LDS acc[128][17]. ds_add_f32.
__global__ __launch_bounds__(256) void gather_final(
    const int* __restrict__ bbase, const int* __restrict__ bcnt,
    const int* __restrict__ pk,
    const unsigned short* __restrict__ Yb,  // y2 bf16 [N][16]
    const float* __restrict__ c2,           // [N][16]
    const float* __restrict__ invdeg,       // [N]
    const float* __restrict__ Wfc,          // [16][2]
    const float* __restrict__ bfc,          // [2]
    float* __restrict__ out, int N)
{
    __shared__ float acc[BK_SIZE * 17];

    const int t = threadIdx.x;
    const int b = blockIdx.x;
    const int base = bbase[b];
    const int cnt  = bcnt[b];
    const int node0 = b * BK_SIZE;

    for (int i = t; i < BK_SIZE * 17; i += 256) acc[i] = 0.f;
    __syncthreads();

    const int sg = t >> 2;        // 64 edge-slots
    const int q  = t & 3;

    for (int e = sg; e < cnt; e += 64) {
        int pkv = pk[base + e];
        int s   = pkv >> BK_SHIFT;
        int dl  = pkv & (BK_SIZE - 1);
        ushort4 v = *(const ushort4*)&Yb[(size_t)s * 16 + q * 4];
        float* ap = &acc[dl * 17 + q * 4];
        unsafeAtomicAdd(ap + 0, bf2f(v.x));
        unsafeAtomicAdd(ap + 1, bf2f(v.y));
        unsafeAtomicAdd(ap + 2, bf2f(v.z));
        unsafeAtomicAdd(ap + 3, bf2f(v.w));
    }
    __syncthreads();

    if (t < BK_SIZE) {
        int node = node0 + t;
        if (node < N) {
            float w = invdeg[node];
            const float* crow = &c2[(size_t)node * 16];
            float o0 = bfc[0], o1 = bfc[1];
            #pragma unroll
            for (int k = 0; k < 16; ++k) {
                float h = fmaxf(crow[k] + acc[t * 17 + k] * w, 0.f);
                o0 += h * Wfc[k * 2 + 0];
                o1 += h * Wfc[k * 2 + 1];
            }
            ((float2*)out)[node] = make_float2(o0, o1);
        }
    }
}

extern "C" void kernel_launch(void* const* d_in, const int* in_sizes, int n_in,
                              void* d_out, int out_size, void* d_ws, size_t ws_size,
                              hipStream_t stream)
{
    const float* x   = (const float*)d_in[0];
    const int*   ei  = (const int*)d_in[1];   // int32 (JAX default)
    const float* W1l = (const float*)d_in[2];
    const float* b1  = (const float*)d_in[3];
    const float* W1r = (const float*)d_in[4];
    const float* W2l = (const float*)d_in[5];
    const float* b2  = (const float*)d_in[6];
    const float* W2r = (const float*)d_in[7];
    const float* Wfc = (const float*)d_in[8];
    const float* bfc = (const float*)d_in[9];
    float* out = (float*)d_out;

    const int N = in_sizes[0] / 128;
    const int E = in_sizes[1] / 2;
    const int* src = ei;
    const int* dst = ei + E;

    const int NBK = (N + BK_SIZE - 1) / BK_SIZE;   // 782

    int*   bucket_cnt  = (int*)d_ws;                // NBK
    int*   bucket_base = bucket_cnt + NBK_MAX;      // NBK
    int*   gcursor     = bucket_base + NBK_MAX;     // NBK
    float* invdeg      = (float*)(gcursor + NBK_MAX);       // N
    int*   pk          = (int*)(invdeg + N);                // E
    unsigned short* y1b = (unsigned short*)(pk + E);        // N*32 bf16
    float* c1          = (float*)(y1b + (size_t)N * 32);    // N*32 f32
    unsigned short* y2b = (unsigned short*)(c1 + (size_t)N * 32); // N*16 bf16
    float* c2          = (float*)(y2b + (size_t)N * 16);    // N*16 f32

    // ---- build bucketed edge list ----
    hipMemsetAsync(bucket_cnt, 0, (size_t)NBK * sizeof(int), stream);
    hist_buckets<<<196, 256, 0, stream>>>(dst, bucket_cnt, E, NBK);
    scan_buckets<<<1, 1024, 0, stream>>>(bucket_cnt, bucket_base, gcursor, NBK);
    {
        int nb = (E + 256 * EPT - 1) / (256 * EPT);
        bin_scatter<<<nb, 256, 0, stream>>>(src, dst, gcursor, pk, E, NBK);
    }

    // ---- layer 1 GEMM (MFMA) ----
    gemm1_mfma<<<256, TPB, 0, stream>>>(x, W1l, W1r, b1, y1b, c1, N);

    // ---- edge-parallel gather1 + relu + gemm2 ----
    gather_gemm2<<<NBK, TPB, 0, stream>>>(
        bucket_base, bucket_cnt, pk, y1b, c1, W2l, W2r, b2,
        invdeg, y2b, c2, N);

    // ---- edge-parallel gather2 + final ----
    gather_final<<<NBK, TPB, 0, stream>>>(
        bucket_base, bucket_cnt, pk, y2b, c2, invdeg, Wfc, bfc, out, N);
}

// Round 14
// 214.509 us; speedup vs baseline: 3.1131x; 3.1131x over previous
//
#include <hip/hip_runtime.h>

#define TPB 256
#define BK_SHIFT 7
#define BK_SIZE 128
#define NBK_MAX 800     // >= ceil(100000/128)=782
#define EPT 32          // edges per thread in bin_scatter chunks
#define CAP 3072        // per-bucket sort capacity (mean 2046, 22 sigma)

typedef __attribute__((ext_vector_type(8))) short bf16x8;
typedef __attribute__((ext_vector_type(4))) float f32x4;

__device__ __forceinline__ unsigned short f2bf(float f) {
    unsigned u = __float_as_uint(f);
    unsigned r = (u + 0x7FFFu + ((u >> 16) & 1u)) >> 16;   // RNE
    return (unsigned short)r;
}
__device__ __forceinline__ float bf2f(unsigned short b) {
    return __uint_as_float((unsigned)b << 16);
}
__device__ __forceinline__ void acc4(float4& a, ushort4 v) {
    a.x += bf2f(v.x); a.y += bf2f(v.y); a.z += bf2f(v.z); a.w += bf2f(v.w);
}

// ---------------- bucket histogram (LDS-privatized, int4 loads) -----------
__global__ __launch_bounds__(256) void hist_buckets(
    const int* __restrict__ dst, int* __restrict__ bcnt, int E, int NBK)
{
    __shared__ int h[NBK_MAX];
    const int t = threadIdx.x;
    for (int i = t; i < NBK; i += 256) h[i] = 0;
    __syncthreads();
    const int E4 = E >> 2;
    for (int e4 = blockIdx.x * blockDim.x + t; e4 < E4; e4 += gridDim.x * blockDim.x) {
        int4 d = ((const int4*)dst)[e4];
        atomicAdd(&h[d.x >> BK_SHIFT], 1);
        atomicAdd(&h[d.y >> BK_SHIFT], 1);
        atomicAdd(&h[d.z >> BK_SHIFT], 1);
        atomicAdd(&h[d.w >> BK_SHIFT], 1);
    }
    if (blockIdx.x == 0) {
        for (int e = E4 * 4 + t; e < E; e += 256)
            atomicAdd(&h[dst[e] >> BK_SHIFT], 1);
    }
    __syncthreads();
    for (int i = t; i < NBK; i += 256)
        if (h[i]) atomicAdd(&bcnt[i], h[i]);
}

// ---------------- scan of bucket counts (one block, NBK<=1024) ------------
__global__ __launch_bounds__(1024) void scan_buckets(
    const int* __restrict__ bcnt, int* __restrict__ bbase,
    int* __restrict__ gcursor, int NBK)
{
    __shared__ int s[1024];
    const int t = threadIdx.x;
    int v = (t < NBK) ? bcnt[t] : 0;
    s[t] = v;
    __syncthreads();
    for (int off = 1; off < 1024; off <<= 1) {
        int u = (t >= off) ? s[t - off] : 0;
        __syncthreads();
        s[t] += u;
        __syncthreads();
    }
    if (t < NBK) {
        int excl = s[t] - v;
        bbase[t]   = excl;
        gcursor[t] = excl;
    }
}

// ---------------- bin scatter: pack edges into bucket-ordered pk[] --------
__global__ __launch_bounds__(256) void bin_scatter(
    const int* __restrict__ src, const int* __restrict__ dst,
    int* __restrict__ gcursor, int* __restrict__ pk, int E, int NBK)
{
    __shared__ int lcnt[NBK_MAX];
    __shared__ int lbase[NBK_MAX];
    __shared__ int lrank[NBK_MAX];
    const int t = threadIdx.x;
    const int e0 = blockIdx.x * (256 * EPT);

    for (int i = t; i < NBK; i += 256) { lcnt[i] = 0; lrank[i] = 0; }
    __syncthreads();

    #pragma unroll 4
    for (int k = 0; k < EPT; ++k) {
        int e = e0 + k * 256 + t;
        if (e < E) atomicAdd(&lcnt[dst[e] >> BK_SHIFT], 1);
    }
    __syncthreads();

    for (int i = t; i < NBK; i += 256) {
        int c = lcnt[i];
        if (c) lbase[i] = atomicAdd(&gcursor[i], c);
    }
    __syncthreads();

    #pragma unroll 4
    for (int k = 0; k < EPT; ++k) {
        int e = e0 + k * 256 + t;
        if (e < E) {
            int d = dst[e], s = src[e];
            int b = d >> BK_SHIFT;
            int r = atomicAdd(&lrank[b], 1);
            pk[lbase[b] + r] = (s << BK_SHIFT) | (d & (BK_SIZE - 1));
        }
    }
}

// ---------------- gemm1 via MFMA:  y1(bf16)=x@W1l,  c1=x@W1r+b1 -----------
__global__ __launch_bounds__(256) void gemm1_mfma(
    const float* __restrict__ A,      // x [N][128]
    const float* __restrict__ Wl,     // [128][32]
    const float* __restrict__ Wr,     // [128][32]
    const float* __restrict__ b,      // [32]
    unsigned short* __restrict__ Yb,  // y1 bf16 [N][32]
    float* __restrict__ C,            // c1 [N][32]
    int N)
{
    const int lane = threadIdx.x & 63;
    const int m    = lane & 15;
    const int quad = lane >> 4;
    const int wave   = blockIdx.x * (blockDim.x >> 6) + (threadIdx.x >> 6);
    const int nwaves = gridDim.x * (blockDim.x >> 6);
    const int ntiles = (N + 15) >> 4;

    bf16x8 Bf[4][4];   // [kc][jt]; jt 0,1 -> Wl; jt 2,3 -> Wr
    #pragma unroll
    for (int kc = 0; kc < 4; ++kc) {
        #pragma unroll
        for (int jt = 0; jt < 4; ++jt) {
            const float* W = (jt < 2) ? Wl : Wr;
            const int col = (jt & 1) * 16 + m;
            #pragma unroll
            for (int j = 0; j < 8; ++j) {
                int k = kc * 32 + quad * 8 + j;
                Bf[kc][jt][j] = (short)f2bf(W[k * 32 + col]);
            }
        }
    }

    const float bias0 = b[m];
    const float bias1 = b[16 + m];

    for (int tile = wave; tile < ntiles; tile += nwaves) {
        const int node0 = tile * 16;
        const int gn = node0 + m;
        const bool okA = gn < N;
        const float* rowp = A + (size_t)gn * 128;

        bf16x8 Af[4];
        #pragma unroll
        for (int kc = 0; kc < 4; ++kc) {
            float4 v0 = make_float4(0.f, 0.f, 0.f, 0.f);
            float4 v1 = make_float4(0.f, 0.f, 0.f, 0.f);
            if (okA) {
                v0 = *(const float4*)&rowp[kc * 32 + quad * 8];
                v1 = *(const float4*)&rowp[kc * 32 + quad * 8 + 4];
            }
            Af[kc][0] = (short)f2bf(v0.x); Af[kc][1] = (short)f2bf(v0.y);
            Af[kc][2] = (short)f2bf(v0.z); Af[kc][3] = (short)f2bf(v0.w);
            Af[kc][4] = (short)f2bf(v1.x); Af[kc][5] = (short)f2bf(v1.y);
            Af[kc][6] = (short)f2bf(v1.z); Af[kc][7] = (short)f2bf(v1.w);
        }

        f32x4 acc[4] = {{0.f,0.f,0.f,0.f},{0.f,0.f,0.f,0.f},
                        {0.f,0.f,0.f,0.f},{0.f,0.f,0.f,0.f}};
        #pragma unroll
        for (int kc = 0; kc < 4; ++kc) {
            #pragma unroll
            for (int jt = 0; jt < 4; ++jt)
                acc[jt] = __builtin_amdgcn_mfma_f32_16x16x32_bf16(
                    Af[kc], Bf[kc][jt], acc[jt], 0, 0, 0);
        }

        const int nodeBase = node0 + quad * 4;
        #pragma unroll
        for (int reg = 0; reg < 4; ++reg) {
            const int node = nodeBase + reg;
            if (node < N) {
                Yb[(size_t)node * 32 + m]      = f2bf(acc[0][reg]);
                Yb[(size_t)node * 32 + 16 + m] = f2bf(acc[1][reg]);
                C [(size_t)node * 32 + m]      = acc[2][reg] + bias0;
                C [(size_t)node * 32 + 16 + m] = acc[3][reg] + bias1;
            }
        }
    }
}

// ------- gather1+relu+gemm2, fused in-LDS counting sort -------------------
// Block b = bucket b (128 nodes): sort pk slice into sidx[] (int atomics,
// native), then R11's per-node walk (8 lanes/node, unroll-4) with LDS idx.
__global__ __launch_bounds__(256) void gather_gemm2(
    const int* __restrict__ bbase, const int* __restrict__ bcnt,
    const int* __restrict__ pk,
    const unsigned short* __restrict__ Yb,  // y1 bf16 [N][32]
    const float* __restrict__ c1,           // [N][32]
    const float* __restrict__ W2l, const float* __restrict__ W2r,
    const float* __restrict__ b2,
    float* __restrict__ invdeg,             // [N] out
    unsigned short* __restrict__ y2b, float* __restrict__ c2, int N)
{
    __shared__ int lcnt[BK_SIZE];
    __shared__ int soff[BK_SIZE];   // inclusive scan
    __shared__ int wcur[BK_SIZE];
    __shared__ int sidx[CAP];

    const int t = threadIdx.x;
    const int b = blockIdx.x;
    const int base = bbase[b];
    const int cnt  = min(bcnt[b], CAP);
    const int node0 = b * BK_SIZE;

    if (t < BK_SIZE) lcnt[t] = 0;
    __syncthreads();

    for (int j = t; j < cnt; j += 256)
        atomicAdd(&lcnt[pk[base + j] & (BK_SIZE - 1)], 1);
    __syncthreads();

    int v = (t < BK_SIZE) ? lcnt[t] : 0;
    if (t < BK_SIZE) soff[t] = v;
    __syncthreads();
    for (int off = 1; off < BK_SIZE; off <<= 1) {
        int u = (t < BK_SIZE && t >= off) ? soff[t - off] : 0;
        __syncthreads();
        if (t < BK_SIZE) soff[t] += u;
        __syncthreads();
    }
    if (t < BK_SIZE) wcur[t] = soff[t] - v;
    __syncthreads();

    for (int j = t; j < cnt; j += 256) {
        int pv = pk[base + j];
        int d  = pv & (BK_SIZE - 1);
        int pos = atomicAdd(&wcur[d], 1);
        sidx[pos] = pv >> BK_SHIFT;
    }
    __syncthreads();

    // per-node walk: 8 lanes/node, 32 nodes per pass, 4 passes
    const int q = t & 7;
    #pragma unroll
    for (int pass = 0; pass < 4; ++pass) {
        const int nl = pass * 32 + (t >> 3);
        const int node = node0 + nl;
        const bool active = node < N;
        float h[4] = {0.f, 0.f, 0.f, 0.f};
        if (active) {
            const int deg = lcnt[nl];
            const int en  = soff[nl];
            const int st  = en - deg;
            const float w = 1.0f / fmaxf((float)deg, 1.0f);
            if (q == 0) invdeg[node] = w;

            float4 a0 = make_float4(0.f,0.f,0.f,0.f);
            float4 a1 = make_float4(0.f,0.f,0.f,0.f);
            float4 a2 = make_float4(0.f,0.f,0.f,0.f);
            float4 a3 = make_float4(0.f,0.f,0.f,0.f);
            int j = st;
            for (; j + 3 < en; j += 4) {
                int s0 = sidx[j], s1 = sidx[j+1], s2 = sidx[j+2], s3 = sidx[j+3];
                ushort4 v0 = *(const ushort4*)&Yb[(size_t)s0 * 32 + q * 4];
                ushort4 v1 = *(const ushort4*)&Yb[(size_t)s1 * 32 + q * 4];
                ushort4 v2 = *(const ushort4*)&Yb[(size_t)s2 * 32 + q * 4];
                ushort4 v3 = *(const ushort4*)&Yb[(size_t)s3 * 32 + q * 4];
                acc4(a0, v0); acc4(a1, v1); acc4(a2, v2); acc4(a3, v3);
            }
            for (; j < en; ++j) {
                ushort4 vv = *(const ushort4*)&Yb[(size_t)sidx[j] * 32 + q * 4];
                acc4(a0, vv);
            }
            float4 acc;
            acc.x = (a0.x + a1.x) + (a2.x + a3.x);
            acc.y = (a0.y + a1.y) + (a2.y + a3.y);
            acc.z = (a0.z + a1.z) + (a2.z + a3.z);
            acc.w = (a0.w + a1.w) + (a2.w + a3.w);

            float4 c = *(const float4*)&c1[(size_t)node * 32 + q * 4];
            h[0] = fmaxf(c.x + acc.x * w, 0.f);
            h[1] = fmaxf(c.y + acc.y * w, 0.f);
            h[2] = fmaxf(c.z + acc.z * w, 0.f);
            h[3] = fmaxf(c.w + acc.w * w, 0.f);
        }

        // gemm2 across the 8-lane group
        const int  j0  = q * 4;
        const bool isY = (j0 < 16);
        const int  jj  = isY ? j0 : (j0 - 16);
        const float* Wb = isY ? W2l : W2r;

        float o0 = 0.f, o1 = 0.f, o2 = 0.f, o3 = 0.f;
        #pragma unroll
        for (int k = 0; k < 32; ++k) {
            float hk = __shfl(h[k & 3], k >> 2, 8);
            float4 wv = *(const float4*)&Wb[k * 16 + jj];
            o0 += hk * wv.x; o1 += hk * wv.y; o2 += hk * wv.z; o3 += hk * wv.w;
        }

        if (active) {
            if (isY) {
                ushort4 r;
                r.x = f2bf(o0); r.y = f2bf(o1); r.z = f2bf(o2); r.w = f2bf(o3);
                *(ushort4*)&y2b[(size_t)node * 16 + jj] = r;
            } else {
                float4 bb = *(const float4*)&b2[jj];
                *(float4*)&c2[(size_t)node * 16 + jj] =
                    make_float4(o0 + bb.x, o1 + bb.y, o2 + bb.z, o3 + bb.w);
            }
        }
    }
}

// ------- gather2+final, fused in-LDS counting sort ------------------------
// Block b = bucket b: re-sort pk, then 4 lanes/node walk y2b rows.
__global__ __launch_bounds__(256) void gather_final(
    const int* __restrict__ bbase, const int* __restrict__ bcnt,
    const int* __restrict__ pk,
    const unsigned short* __restrict__ Yb,  // y2 bf16 [N][16]
    const float* __restrict__ c2,           // [N][16]
    const float* __restrict__ invdeg,       // [N]
    const float* __restrict__ Wfc,          // [16][2]
    const float* __restrict__ bfc,          // [2]
    float* __restrict__ out, int N)
{
    __shared__ int lcnt[BK_SIZE];
    __shared__ int soff[BK_SIZE];
    __shared__ int wcur[BK_SIZE];
    __shared__ int sidx[CAP];

    const int t = threadIdx.x;
    const int b = blockIdx.x;
    const int base = bbase[b];
    const int cnt  = min(bcnt[b], CAP);
    const int node0 = b * BK_SIZE;

    if (t < BK_SIZE) lcnt[t] = 0;
    __syncthreads();

    for (int j = t; j < cnt; j += 256)
        atomicAdd(&lcnt[pk[base + j] & (BK_SIZE - 1)], 1);
    __syncthreads();

    int v = (t < BK_SIZE) ? lcnt[t] : 0;
    if (t < BK_SIZE) soff[t] = v;
    __syncthreads();
    for (int off = 1; off < BK_SIZE; off <<= 1) {
        int u = (t < BK_SIZE && t >= off) ? soff[t - off] : 0;
        __syncthreads();
        if (t < BK_SIZE) soff[t] += u;
        __syncthreads();
    }
    if (t < BK_SIZE) wcur[t] = soff[t] - v;
    __syncthreads();

    for (int j = t; j < cnt; j += 256) {
        int pv = pk[base + j];
        int d  = pv & (BK_SIZE - 1);
        int pos = atomicAdd(&wcur[d], 1);
        sidx[pos] = pv >> BK_SHIFT;
    }
    __syncthreads();

    // per-node walk: 4 lanes/node, 64 nodes per pass, 2 passes
    const int q = t & 3;
    #pragma unroll
    for (int pass = 0; pass < 2; ++pass) {
        const int nl = pass * 64 + (t >> 2);
        const int node = node0 + nl;
        if (node < N) {
            const int deg = lcnt[nl];
            const int en  = soff[nl];
            const int st  = en - deg;
            const float w = invdeg[node];

            float4 a0 = make_float4(0.f,0.f,0.f,0.f);
            float4 a1 = make_float4(0.f,0.f,0.f,0.f);
            float4 a2 = make_float4(0.f,0.f,0.f,0.f);
            float4 a3 = make_float4(0.f,0.f,0.f,0.f);
            int j = st;
            for (; j + 3 < en; j += 4) {
                int s0 = sidx[j], s1 = sidx[j+1], s2 = sidx[j+2], s3 = sidx[j+3];
                ushort4 v0 = *(const ushort4*)&Yb[(size_t)s0 * 16 + q * 4];
                ushort4 v1 = *(const ushort4*)&Yb[(size_t)s1 * 16 + q * 4];
                ushort4 v2 = *(const ushort4*)&Yb[(size_t)s2 * 16 + q * 4];
                ushort4 v3 = *(const ushort4*)&Yb[(size_t)s3 * 16 + q * 4];
                acc4(a0, v0); acc4(a1, v1); acc4(a2, v2); acc4(a3, v3);
            }
            for (; j < en; ++j) {
                ushort4 vv = *(const ushort4*)&Yb[(size_t)sidx[j] * 16 + q * 4];
                acc4(a0, vv);
            }
            float4 acc;
            acc.x = (a0.x + a1.x) + (a2.x + a3.x);
            acc.y = (a0.y + a1.y) + (a2.y + a3.y);
            acc.z = (a0.z + a1.z) + (a2.z + a3.z);
            acc.w = (a0.w + a1.w) + (a2.w + a3.w);

            float4 c = *(const float4*)&c2[(size_t)node * 16 + q * 4];
            float h0 = fmaxf(c.x + acc.x * w, 0.f);
            float h1 = fmaxf(c.y + acc.y * w, 0.f);
            float h2 = fmaxf(c.z + acc.z * w, 0.f);
            float h3 = fmaxf(c.w + acc.w * w, 0.f);

            const float* Wq = &Wfc[q * 8];
            float o0 = h0 * Wq[0] + h1 * Wq[2] + h2 * Wq[4] + h3 * Wq[6];
            float o1 = h0 * Wq[1] + h1 * Wq[3] + h2 * Wq[5] + h3 * Wq[7];

            o0 += __shfl_xor(o0, 1); o0 += __shfl_xor(o0, 2);
            o1 += __shfl_xor(o1, 1); o1 += __shfl_xor(o1, 2);

            if (q == 0) ((float2*)out)[node] = make_float2(o0 + bfc[0], o1 + bfc[1]);
        } else {
            // keep shuffles convergent within the wave (no-op values)
            float z = 0.f;
            z += __shfl_xor(z, 1); z += __shfl_xor(z, 2);
        }
    }
}

extern "C" void kernel_launch(void* const* d_in, const int* in_sizes, int n_in,
                              void* d_out, int out_size, void* d_ws, size_t ws_size,
                              hipStream_t stream)
{
    const float* x   = (const float*)d_in[0];
    const int*   ei  = (const int*)d_in[1];   // int32 (JAX default)
    const float* W1l = (const float*)d_in[2];
    const float* b1  = (const float*)d_in[3];
    const float* W1r = (const float*)d_in[4];
    const float* W2l = (const float*)d_in[5];
    const float* b2  = (const float*)d_in[6];
    const float* W2r = (const float*)d_in[7];
    const float* Wfc = (const float*)d_in[8];
    const float* bfc = (const float*)d_in[9];
    float* out = (float*)d_out;

    const int N = in_sizes[0] / 128;
    const int E = in_sizes[1] / 2;
    const int* src = ei;
    const int* dst = ei + E;

    const int NBK = (N + BK_SIZE - 1) / BK_SIZE;   // 782

    int*   bucket_cnt  = (int*)d_ws;                // NBK
    int*   bucket_base = bucket_cnt + NBK_MAX;      // NBK
    int*   gcursor     = bucket_base + NBK_MAX;     // NBK
    float* invdeg      = (float*)(gcursor + NBK_MAX);       // N
    int*   pk          = (int*)(invdeg + N);                // E
    unsigned short* y1b = (unsigned short*)(pk + E);        // N*32 bf16
    float* c1          = (float*)(y1b + (size_t)N * 32);    // N*32 f32
    unsigned short* y2b = (unsigned short*)(c1 + (size_t)N * 32); // N*16 bf16
    float* c2          = (float*)(y2b + (size_t)N * 16);    // N*16 f32

    // ---- build bucketed edge list ----
    hipMemsetAsync(bucket_cnt, 0, (size_t)NBK * sizeof(int), stream);
    hist_buckets<<<196, 256, 0, stream>>>(dst, bucket_cnt, E, NBK);
    scan_buckets<<<1, 1024, 0, stream>>>(bucket_cnt, bucket_base, gcursor, NBK);
    {
        int nb = (E + 256 * EPT - 1) / (256 * EPT);
        bin_scatter<<<nb, 256, 0, stream>>>(src, dst, gcursor, pk, E, NBK);
    }

    // ---- layer 1 GEMM (MFMA) ----
    gemm1_mfma<<<256, TPB, 0, stream>>>(x, W1l, W1r, b1, y1b, c1, N);

    // ---- fused sort + gather1 + relu + gemm2 ----
    gather_gemm2<<<NBK, TPB, 0, stream>>>(
        bucket_base, bucket_cnt, pk, y1b, c1, W2l, W2r, b2,
        invdeg, y2b, c2, N);

    // ---- fused sort + gather2 + final ----
    gather_final<<<NBK, TPB, 0, stream>>>(
        bucket_base, bucket_cnt, pk, y2b, c2, invdeg, Wfc, bfc, out, N);
}